// Round 9
// baseline (149.720 us; speedup 1.0000x reference)
//
#include <hip/hip_runtime.h>

// Problem constants: B=16 batches, A=5 agents, C=512 channels, H=W=16.
#define NB 16
#define NA 5
#define NC 512
#define HW 256
#define NITEM 1024               // (batch, 8ch-group) items
#define NBLK 1792                // 7 blocks/CU (LDS 20.5KB x 7 = 143KB <= 160KB)

typedef float f4 __attribute__((ext_vector_type(4)));
typedef _Float16 h8 __attribute__((ext_vector_type(8)));   // 16 B = ds b128

static __device__ __forceinline__ h8 splat8(float v) {
    const _Float16 h = (_Float16)v;
    h8 r = {h, h, h, h, h, h, h, h};
    return r;
}

// Work-stealing fusion. Item = (batch b, 8-channel group). A block grabs items
// from a global atomic queue until empty -> perfect CU load balance no matter
// how n (and thus per-item pair count) is distributed, and no dependence on
// dispatch order. Per item: stage the n agent slabs once (fp16, px-major h8,
// one ds_read_b128 = one tap x 8 channels), then thread=pixel computes all 5
// output agents: exact-f32 residual + collapsed 16-tap pair gathers with
// channel-amortized weights. 2 barriers per item total.
__global__ __launch_bounds__(256) void fafmimo_steal_kernel(
    const float* __restrict__ feat,   // [A*B][C][256], feat[a*B+b] = local[b][a]
    const float* __restrict__ trans,  // [B][A][A][4][4]
    const int*   __restrict__ numa,   // [B][A], use [:,0]
    float*       __restrict__ out,    // [A*B][C][256]
    unsigned*    __restrict__ ctr)    // work-queue cursor (zeroed via memset)
{
    __shared__ h8 slab[NA][HW];       // 20 KiB
    __shared__ unsigned s_item;

    const int tid = threadIdx.x;
    const int px  = tid;              // pixel 0..255
    const int x   = px & 15, y = px >> 4;

    if (tid == 0) s_item = atomicAdd(ctr, 1u);
    __syncthreads();
    unsigned item = s_item;

    while (item < NITEM) {
        const int b  = item & (NB - 1);
        const int g  = item >> 4;
        const int c0 = g << 3;
        const int n  = numa[b * NA];  // block-uniform

        // ---- stage slabs for agents j < n (only used when n > 1) ----
        if (n > 1) {
            for (int j = 0; j < n; ++j) {
                const float* src = feat + ((size_t)(j * NB + b) * NC + c0) * HW + px;
                h8 v;
#pragma unroll
                for (int k = 0; k < 8; ++k) v[k] = (_Float16)src[k * HW];
                slab[j][px] = v;
            }
        }
        __syncthreads();              // slabs visible
        if (tid == 0) s_item = atomicAdd(ctr, 1u);   // grab next (published below)

        // ---- compute all 5 output agents ----
        for (int i = 0; i < NA; ++i) {
            const size_t base = ((size_t)(i * NB + b) * NC + c0) * HW + px;
            float own[8];             // exact-f32 residual
#pragma unroll
            for (int k = 0; k < 8; ++k) own[k] = feat[base + k * HW];

            h8 pacc = splat8(0.0f);
            if (i < n && n > 1) {
                for (int j = 0; j < n; ++j) {
                    if (j == i) continue;     // uniform control flow

                    const float* tb = trans + (size_t)(((b * NA) + i) * NA + j) * 16;
                    const f4 row0 = *(const f4*)tb;        // r00 r01 _ tx
                    const f4 row1 = *(const f4*)(tb + 4);  // r10 r11 _ ty
                    const float r00 = row0.x, r01 = row0.y;
                    const float r10 = row1.x, r11 = row1.y;

                    // collapsed two-stage warp: 16 (tap, weight) per pixel
                    int   ta[16];
                    float wa[16];
                    {
                        const float dx = 0.25f * row0.w;
                        const float dy = -0.25f * row1.w;
                        const float fdx = floorf(dx), fdy = floorf(dy);
                        const float tx1 = dx - fdx, tx0 = 1.0f - tx1;
                        const float ty1 = dy - fdy, ty0 = 1.0f - ty1;
                        const int ox = x + (int)fdx;
                        const int oy = y + (int)fdy;
                        const float fox = (float)ox - 7.5f;
                        const float foy = (float)oy - 7.5f;
                        const float bxr = r00 * fox + r01 * foy + 7.5f;
                        const float byr = r10 * fox + r11 * foy + 7.5f;
                        int t = 0;
#pragma unroll
                        for (int sy = 0; sy < 2; ++sy)
#pragma unroll
                        for (int sx = 0; sx < 2; ++sx) {
                            const int tox = ox + sx, toy = oy + sy;
                            const bool in2 = (tox >= 0) && (tox < 16) &&
                                             (toy >= 0) && (toy < 16);
                            const float ws = in2 ? (sx ? tx1 : tx0) * (sy ? ty1 : ty0)
                                                 : 0.0f;
                            const float cx = bxr + (float)sx * r00 + (float)sy * r01;
                            const float cy = byr + (float)sx * r10 + (float)sy * r11;
                            const float fx0 = floorf(cx), fy0 = floorf(cy);
                            const float wx1 = cx - fx0, wy1 = cy - fy0;
                            const int ix0 = (int)fx0, iy0 = (int)fy0;
                            const float mx0 = (ix0 >= 0 && ix0 < 16) ? 1.0f - wx1 : 0.0f;
                            const float mx1 = (ix0 + 1 >= 0 && ix0 + 1 < 16) ? wx1 : 0.0f;
                            const float my0 = ((iy0 >= 0 && iy0 < 16) ? 1.0f - wy1 : 0.0f) * ws;
                            const float my1 = ((iy0 + 1 >= 0 && iy0 + 1 < 16) ? wy1 : 0.0f) * ws;
                            const int cx0 = min(max(ix0, 0), 15);
                            const int cx1 = min(max(ix0 + 1, 0), 15);
                            const int cy0 = min(max(iy0, 0), 15);
                            const int cy1 = min(max(iy0 + 1, 0), 15);
                            ta[t] = cy0 * 16 + cx0; wa[t++] = mx0 * my0;
                            ta[t] = cy0 * 16 + cx1; wa[t++] = mx1 * my0;
                            ta[t] = cy1 * 16 + cx0; wa[t++] = mx0 * my1;
                            ta[t] = cy1 * 16 + cx1; wa[t++] = mx1 * my1;
                        }
                    }

                    // batched gather: 16 b128 loads, then fma tree
                    const h8* sj = &slab[j][0];
                    h8 tv[16];
#pragma unroll
                    for (int t = 0; t < 16; ++t) tv[t] = sj[ta[t]];
#pragma unroll
                    for (int t = 0; t < 16; ++t) pacc += tv[t] * splat8(wa[t]);
                }
            }

            float* dst = out + base;
#pragma unroll
            for (int k = 0; k < 8; ++k) dst[k * HW] = own[k] + (float)pacc[k];
        }

        __syncthreads();              // slab reads done + s_item published
        item = s_item;
    }
}

extern "C" void kernel_launch(void* const* d_in, const int* in_sizes, int n_in,
                              void* d_out, int out_size, void* d_ws, size_t ws_size,
                              hipStream_t stream) {
    const float* feat  = (const float*)d_in[0];
    const float* trans = (const float*)d_in[1];
    const int*   numa  = (const int*)d_in[2];
    float* out = (float*)d_out;
    unsigned* ctr = (unsigned*)d_ws;

    hipMemsetAsync(ctr, 0, sizeof(unsigned), stream);   // capture-safe stream op
    fafmimo_steal_kernel<<<dim3(NBLK), dim3(256), 0, stream>>>(
        feat, trans, numa, out, ctr);
}

// Round 10
// 113.202 us; speedup vs baseline: 1.3226x; 1.3226x over previous
//
#include <hip/hip_runtime.h>

// Problem constants: B=16 batches, A=5 agents, C=512 channels, H=W=16.
#define NB 16
#define NA 5
#define NC 512
#define HW 256
#define NBLK 1024                // (batch, 8ch-group) items; 4 blocks/CU exactly

typedef float f4 __attribute__((ext_vector_type(4)));
typedef _Float16 h8 __attribute__((ext_vector_type(8)));   // 16 B = ds b128

static __device__ __forceinline__ h8 splat8(float v) {
    const _Float16 h = (_Float16)v;
    h8 r = {h, h, h, h, h, h, h, h};
    return r;
}

// Block = (batch b, 8-channel group). CRITICAL mapping detail: b = (blk>>6)&15
// so a CU's resident blocks {c, c+256, c+512, c+768} carry FOUR DIFFERENT
// batches (b, b+4, b+8, b+12) -> per-CU load = sum of 4 independent draws of
// n(n-1) instead of 4x one draw (R8's b=blk&15 aliased all residents to one
// batch: max-CU 80 pair-waves, 57.6us). No atomics (R9: hot-counter RMW
// serialization cost ~80us). One barrier total. Per pair: 16-entry collapsed
// tap table computed once per pixel, 16 back-to-back ds_read_b128 (tap x 8ch),
// fp16 pk-fma; residual exact f32.
__global__ __launch_bounds__(256, 4) void fafmimo_mix_kernel(
    const float* __restrict__ feat,   // [A*B][C][256], feat[a*B+b] = local[b][a]
    const float* __restrict__ trans,  // [B][A][A][4][4]
    const int*   __restrict__ numa,   // [B][A], use [:,0]
    float*       __restrict__ out)    // [A*B][C][256]
{
    __shared__ h8 slab[NA][HW];       // 20 KiB

    const int blk = blockIdx.x;
    const int g   = blk & 63;         // adjacent blocks: same batch, diff channels
    const int b   = (blk >> 6) & 15;  // resident set on a CU spans 4 batches
    const int c0  = g << 3;
    const int px  = threadIdx.x;      // pixel 0..255
    const int x   = px & 15, y = px >> 4;
    const int n   = numa[b * NA];     // block-uniform

    // ---- stage slabs for agents j < n (fp16, px-major, 8ch interleaved) ----
    if (n > 1) {
        for (int j = 0; j < n; ++j) {
            const float* src = feat + ((size_t)(j * NB + b) * NC + c0) * HW + px;
            h8 v;
#pragma unroll
            for (int k = 0; k < 8; ++k) v[k] = (_Float16)src[k * HW];
            slab[j][px] = v;
        }
    }
    __syncthreads();                  // the only barrier

    // ---- compute all 5 output agents ----
    for (int i = 0; i < NA; ++i) {
        const size_t base = ((size_t)(i * NB + b) * NC + c0) * HW + px;
        float own[8];                 // exact-f32 residual (overlaps gather below)
#pragma unroll
        for (int k = 0; k < 8; ++k) own[k] = feat[base + k * HW];

        h8 pacc = splat8(0.0f);
        if (i < n && n > 1) {
            for (int j = 0; j < n; ++j) {
                if (j == i) continue; // uniform control flow

                const float* tb = trans + (size_t)(((b * NA) + i) * NA + j) * 16;
                const f4 row0 = *(const f4*)tb;        // r00 r01 _ tx
                const f4 row1 = *(const f4*)(tb + 4);  // r10 r11 _ ty
                const float r00 = row0.x, r01 = row0.y;
                const float r10 = row1.x, r11 = row1.y;

                // collapsed two-stage warp: 16 (tap, weight) per pixel
                int   ta[16];
                float wa[16];
                {
                    const float dx = 0.25f * row0.w;
                    const float dy = -0.25f * row1.w;
                    const float fdx = floorf(dx), fdy = floorf(dy);
                    const float tx1 = dx - fdx, tx0 = 1.0f - tx1;
                    const float ty1 = dy - fdy, ty0 = 1.0f - ty1;
                    const int ox = x + (int)fdx;
                    const int oy = y + (int)fdy;
                    const float fox = (float)ox - 7.5f;
                    const float foy = (float)oy - 7.5f;
                    const float bxr = r00 * fox + r01 * foy + 7.5f;
                    const float byr = r10 * fox + r11 * foy + 7.5f;
                    int t = 0;
#pragma unroll
                    for (int sy = 0; sy < 2; ++sy)
#pragma unroll
                    for (int sx = 0; sx < 2; ++sx) {
                        const int tox = ox + sx, toy = oy + sy;
                        const bool in2 = (tox >= 0) && (tox < 16) &&
                                         (toy >= 0) && (toy < 16);
                        const float ws = in2 ? (sx ? tx1 : tx0) * (sy ? ty1 : ty0)
                                             : 0.0f;
                        const float cx = bxr + (float)sx * r00 + (float)sy * r01;
                        const float cy = byr + (float)sx * r10 + (float)sy * r11;
                        const float fx0 = floorf(cx), fy0 = floorf(cy);
                        const float wx1 = cx - fx0, wy1 = cy - fy0;
                        const int ix0 = (int)fx0, iy0 = (int)fy0;
                        const float mx0 = (ix0 >= 0 && ix0 < 16) ? 1.0f - wx1 : 0.0f;
                        const float mx1 = (ix0 + 1 >= 0 && ix0 + 1 < 16) ? wx1 : 0.0f;
                        const float my0 = ((iy0 >= 0 && iy0 < 16) ? 1.0f - wy1 : 0.0f) * ws;
                        const float my1 = ((iy0 + 1 >= 0 && iy0 + 1 < 16) ? wy1 : 0.0f) * ws;
                        const int cx0 = min(max(ix0, 0), 15);
                        const int cx1 = min(max(ix0 + 1, 0), 15);
                        const int cy0 = min(max(iy0, 0), 15);
                        const int cy1 = min(max(iy0 + 1, 0), 15);
                        ta[t] = cy0 * 16 + cx0; wa[t++] = mx0 * my0;
                        ta[t] = cy0 * 16 + cx1; wa[t++] = mx1 * my0;
                        ta[t] = cy1 * 16 + cx0; wa[t++] = mx0 * my1;
                        ta[t] = cy1 * 16 + cx1; wa[t++] = mx1 * my1;
                    }
                }

                // batched gather: 16 b128 loads back-to-back, then fma tree
                const h8* sj = &slab[j][0];
                h8 tv[16];
#pragma unroll
                for (int t = 0; t < 16; ++t) tv[t] = sj[ta[t]];
#pragma unroll
                for (int t = 0; t < 16; ++t) pacc += tv[t] * splat8(wa[t]);
            }
        }

        float* dst = out + base;
#pragma unroll
        for (int k = 0; k < 8; ++k) dst[k * HW] = own[k] + (float)pacc[k];
    }
}

extern "C" void kernel_launch(void* const* d_in, const int* in_sizes, int n_in,
                              void* d_out, int out_size, void* d_ws, size_t ws_size,
                              hipStream_t stream) {
    const float* feat  = (const float*)d_in[0];
    const float* trans = (const float*)d_in[1];
    const int*   numa  = (const int*)d_in[2];
    float* out = (float*)d_out;

    fafmimo_mix_kernel<<<dim3(NBLK), dim3(256), 0, stream>>>(
        feat, trans, numa, out);
}